// Round 4
// baseline (404.114 us; speedup 1.0000x reference)
//
#include <hip/hip_runtime.h>
#include <math.h>

#define NNODES 100000
#define NEDGES 1600000
#define ETOT   (NEDGES + NNODES)   // self-loops appended

// bucket-major CSR build
#define BSZ   128                         // dst nodes per bucket (dst >> 7)
#define KBUCK ((NNODES + BSZ - 1) / BSZ)  // 782 buckets
#define CAP   2816                        // max TOTAL entries per bucket
#define NSUB  8                           // per-XCD sub-buckets
#define CAPS  768                         // per sub-bucket (survives XCD skew; R6 lesson)
#define CPAD  16                          // counter padding (one per 64B line)

#define GEMMB 1563                        // gemm0 blocks (64 nodes each)
#define EPT   4                           // edges per thread in bucket half
#define BUCKB ((ETOT + 1024 - 1) / 1024)  // 1661 bucket blocks

__device__ __forceinline__ int xcc_id() {
    int x;
    asm volatile("s_getreg_b32 %0, hwreg(HW_REG_XCC_ID)" : "=s"(x));
    return x & (NSUB - 1);
}

// fp32 -> bf16 with round-to-nearest-even (bit-level, no NaN inputs here)
__device__ __forceinline__ unsigned short f2bf(float f) {
    unsigned u = __float_as_uint(f);
    return (unsigned short)((u + 0x7FFFu + ((u >> 16) & 1u)) >> 16);
}

// ===========================================================================
__global__ void zero_cnt(int* __restrict__ cnt) {
    int i = blockIdx.x * blockDim.x + threadIdx.x;
    if (i < KBUCK * NSUB * CPAD) cnt[i] = 0;
}

// ---------------------------------------------------------------------------
// bucket build: append (dst-low, src) to XCD-local sub-bucket. 4-edge ILP.
// R3: standalone kernel (was fused with gemm0 — confounded occupancy/latency).
__global__ __launch_bounds__(256) void bucket_build(
        const int* __restrict__ ei, int* __restrict__ cnt,
        unsigned int* __restrict__ stage) {
    const int bb = blockIdx.x;
    const int t = threadIdx.x;
    const int xg = xcc_id();
#pragma unroll
    for (int r = 0; r < EPT; ++r) {
        int e = bb * 1024 + r * 256 + t;
        if (e < ETOT) {
            int src, dst;
            if (e < NEDGES) { src = ei[e]; dst = ei[NEDGES + e]; }
            else            { src = dst = e - NEDGES; }
            int sb = (dst >> 7) * NSUB + xg;
            int pos = atomicAdd(&cnt[sb * CPAD], 1);
            if (pos < CAPS)
                stage[(size_t)sb * CAPS + pos] =
                    ((unsigned)(dst & 127) << 24) | (unsigned)src;
        }
    }
}

// ---------------------------------------------------------------------------
// gemm0: h0 = x @ W0.T (64 out-ch, stored bf16) + attention scalars (fp32).
// R3: standalone kernel, full-128K LDS staging, 3-deep x register prefetch
// pipeline (xa/xb/xc) to cover global-load latency (prev: MLP≈1, waves
// spent ~85% of life on vmcnt).
__global__ __launch_bounds__(256) void gemm0_k(
        const float* __restrict__ x, const float* __restrict__ W,
        const float* __restrict__ att,
        unsigned short* __restrict__ h0b,
        float* __restrict__ ai, float* __restrict__ aj) {
    __shared__ float Wt[128 * 68];
    const int tid = threadIdx.x;
    const int nb = blockIdx.x * 64;

    const int lane = tid & 63;
    const int w    = tid >> 6;
    const int ocg  = lane & 15;          // owns out-ch ocg*4 .. ocg*4+3
    const int ng   = lane >> 4;
    const int nodeLocal = w * 16 + ng * 4;

    const float* xp[4];
#pragma unroll
    for (int j = 0; j < 4; ++j) {
        int node = nb + nodeLocal + j;
        xp[j] = x + (size_t)(node < NNODES ? node : NNODES - 1) * 128;
    }

    // x pipeline: xa = chunk g, xb = g+1, xc = g+2 (prefetch g+3 in loop).
    // Issued BEFORE staging so they overlap the W stage + barrier.
    float4 xa[4], xb[4], xc[4];
#pragma unroll
    for (int j = 0; j < 4; ++j) {
        xa[j] = *(const float4*)(xp[j] + 0);
        xb[j] = *(const float4*)(xp[j] + 4);
        xc[j] = *(const float4*)(xp[j] + 8);
    }

    for (int i = tid; i < 128 * 64; i += 256) {
        int oc = i >> 7, k = i & 127;
        Wt[k * 68 + oc] = W[i];
    }
    __syncthreads();

    float4 acc[4];
#pragma unroll
    for (int j = 0; j < 4; ++j) acc[j] = make_float4(0.f, 0.f, 0.f, 0.f);

#pragma unroll 4
    for (int k4 = 0; k4 < 32; ++k4) {
        const int kb = k4 * 4;
        int kpf = kb + 12; if (kpf > 124) kpf = 124;   // clamp: redundant L1-hit tail
        // prefetch chunk g+3
        float4 xn0 = *(const float4*)(xp[0] + kpf);
        float4 xn1 = *(const float4*)(xp[1] + kpf);
        float4 xn2 = *(const float4*)(xp[2] + kpf);
        float4 xn3 = *(const float4*)(xp[3] + kpf);
        // W fragments from LDS (conflict-free: 16 ocg x float4 = 32 banks)
        float4 wv0 = *(const float4*)&Wt[(kb + 0) * 68 + ocg * 4];
        float4 wv1 = *(const float4*)&Wt[(kb + 1) * 68 + ocg * 4];
        float4 wv2 = *(const float4*)&Wt[(kb + 2) * 68 + ocg * 4];
        float4 wv3 = *(const float4*)&Wt[(kb + 3) * 68 + ocg * 4];
#pragma unroll
        for (int j = 0; j < 4; ++j) {
            float4 xv = xa[j];
            acc[j].x += xv.x * wv0.x + xv.y * wv1.x + xv.z * wv2.x + xv.w * wv3.x;
            acc[j].y += xv.x * wv0.y + xv.y * wv1.y + xv.z * wv2.y + xv.w * wv3.y;
            acc[j].z += xv.x * wv0.z + xv.y * wv1.z + xv.z * wv2.z + xv.w * wv3.z;
            acc[j].w += xv.x * wv0.w + xv.y * wv1.w + xv.z * wv2.w + xv.w * wv3.w;
        }
        // rotate pipeline (static indices -> registers)
        xa[0] = xb[0]; xa[1] = xb[1]; xa[2] = xb[2]; xa[3] = xb[3];
        xb[0] = xc[0]; xb[1] = xc[1]; xb[2] = xc[2]; xb[3] = xc[3];
        xc[0] = xn0;   xc[1] = xn1;   xc[2] = xn2;   xc[3] = xn3;
    }

    const int ocb = ocg * 4;
    float ati[4], atj[4];
#pragma unroll
    for (int i = 0; i < 4; ++i) {
        ati[i] = att[ocb + i];
        atj[i] = att[64 + ocb + i];
    }

#pragma unroll
    for (int j = 0; j < 4; ++j) {
        int nodeG = nb + nodeLocal + j;
        float pai = acc[j].x * ati[0] + acc[j].y * ati[1] + acc[j].z * ati[2] + acc[j].w * ati[3];
        float paj = acc[j].x * atj[0] + acc[j].y * atj[1] + acc[j].z * atj[2] + acc[j].w * atj[3];
#pragma unroll
        for (int off = 1; off < 16; off <<= 1) {
            pai += __shfl_xor(pai, off, 64);
            paj += __shfl_xor(paj, off, 64);
        }
        if (nodeG < NNODES) {
            unsigned p0 = ((unsigned)f2bf(acc[j].y) << 16) | f2bf(acc[j].x);
            unsigned p1 = ((unsigned)f2bf(acc[j].w) << 16) | f2bf(acc[j].z);
            *(uint2*)&h0b[(size_t)nodeG * 64 + ocb] = make_uint2(p0, p1);
            if (ocg == 0) { ai[nodeG] = pai; aj[nodeG] = paj; }
        }
    }
}

// ===========================================================================
__global__ void bucket_scan(const int* __restrict__ cnt, int* __restrict__ bstart) {
    __shared__ int wsum[16];
    const int t = threadIdx.x;                      // 1024 threads
    int x = 0;
    if (t < KBUCK) {
#pragma unroll
        for (int s = 0; s < NSUB; ++s) x += min(cnt[(t * NSUB + s) * CPAD], CAPS);
    }
    int lane = t & 63, w = t >> 6;
    int inc = x;
#pragma unroll
    for (int off = 1; off < 64; off <<= 1) {
        int u = __shfl_up(inc, off, 64);
        if (lane >= off) inc += u;
    }
    if (lane == 63) wsum[w] = inc;
    __syncthreads();
    if (t == 0) {
        int s = 0;
#pragma unroll
        for (int j = 0; j < 16; ++j) { int y = wsum[j]; wsum[j] = s; s += y; }
    }
    __syncthreads();
    int excl = inc - x + wsum[w];
    if (t < KBUCK) bstart[t] = excl;
    if (t == KBUCK) bstart[KBUCK] = excl;
}

__global__ __launch_bounds__(256) void bucket_scatter(
        const int* __restrict__ cnt, const int* __restrict__ bstart,
        const unsigned int* __restrict__ stage, int* __restrict__ rowstart,
        int* __restrict__ csr_src) {
    __shared__ unsigned int ent[CAP];
    __shared__ int hist[BSZ];
    __shared__ int scnt[NSUB];
    __shared__ int soff[NSUB + 1];
    __shared__ int wtot;
    const int b = blockIdx.x, t = threadIdx.x;
    const int n0 = b * BSZ;
    const int base = bstart[b];

    if (t < BSZ) hist[t] = 0;
    if (t < NSUB) scnt[t] = min(cnt[(b * NSUB + t) * CPAD], CAPS);
    __syncthreads();
    if (t == 0) {
        int s = 0;
#pragma unroll
        for (int x = 0; x < NSUB; ++x) { soff[x] = s; s += scnt[x]; }
        soff[NSUB] = s;
    }
    __syncthreads();

#pragma unroll
    for (int x = 0; x < NSUB; ++x) {
        const int cx = scnt[x];
        const int ox = soff[x];
        const unsigned int* sp = stage + (size_t)(b * NSUB + x) * CAPS;
        for (int i = t; i < cx; i += 256) {
            unsigned int v = sp[i];
            ent[ox + i] = v;
            atomicAdd(&hist[v >> 24], 1);
        }
    }
    __syncthreads();
    const int c = soff[NSUB];

    int lane = t & 63, w = t >> 6;
    int v = (t < BSZ) ? hist[t] : 0;
    int inc = v;
#pragma unroll
    for (int off = 1; off < 64; off <<= 1) {
        int u = __shfl_up(inc, off, 64);
        if (lane >= off) inc += u;
    }
    if (t == 63) wtot = inc;
    __syncthreads();
    int excl = inc - v + ((w == 1) ? wtot : 0);
    if (t < BSZ) {
        int node = n0 + t;
        if (node <= NNODES) rowstart[node] = base + excl;
    }
    __syncthreads();
    if (t < BSZ) hist[t] = excl;
    __syncthreads();
    for (int i = t; i < c; i += 256) {
        unsigned int e = ent[i];
        int pos = atomicAdd(&hist[e >> 24], 1);
        csr_src[base + pos] = (int)(e & 0xFFFFFFu);
    }
}

// ===========================================================================
// Layer-0 aggregation (bf16 h0 gather) + fused gemm1 (fp32) -> bf16 h1 +
// layer-1 attention scalars. Single-pass softmax (normalization is linear).
// Inner loop: 8 edges/trip x 8 lanes/edge (uint4 = 8ch/lane), guarded tail.
// ===========================================================================
__global__ __launch_bounds__(256) void agg_gemm1(
        const int* __restrict__ rowstart, const int* __restrict__ csr_src,
        const float* __restrict__ aj,
        const float* __restrict__ ai, const unsigned short* __restrict__ h0b,
        const float* __restrict__ W1, const float* __restrict__ att1,
        unsigned short* __restrict__ h1b, float* __restrict__ ai1,
        float* __restrict__ aj1) {
    __shared__ float  W1L[64 * 68];     // oc-major, stride 68 (2-way banks: free)
    __shared__ int2   escr[4][64];      // per-wave (src, e) scratch
    __shared__ float  rowbuf[4][64];    // per-wave combined row

    const int tid = threadIdx.x;
    for (int i = tid; i < 64 * 64; i += 256) {
        int oc = i >> 6, k = i & 63;
        W1L[oc * 68 + k] = (oc < 40) ? W1[oc * 64 + k] : 0.0f;
    }
    __syncthreads();

    const int lane = tid & 63;
    const int wid  = tid >> 6;
    const int n = blockIdx.x * 4 + wid;
    if (n >= NNODES) return;

    const int start = rowstart[n];
    const int end   = rowstart[n + 1];
    const float ain = ai[n];

    const int cg = lane & 7;            // 8 channel-groups of 8 ch
    const int sg = lane >> 3;           // 8 edge slots
    float4 accA = make_float4(0.f, 0.f, 0.f, 0.f);
    float4 accB = make_float4(0.f, 0.f, 0.f, 0.f);
    float  esum = 0.0f;

    for (int c = start; c < end; c += 64) {
        int rem = end - c;
        int cnt = (rem < 64) ? rem : 64;            // wave-uniform
        int s = 0; float e = 0.0f;
        if (lane < cnt) {
            s = csr_src[c + lane];
            float t = ain + aj[s];
            t = (t > 0.0f) ? t : 0.2f * t;
            e = __expf(t);
        }
        escr[wid][lane] = make_int2(s, __float_as_int(e));
        esum += e;
        for (int j0 = 0; j0 < cnt; j0 += 8) {       // uniform trips (R3 lesson)
            int j = j0 + sg;
            if (j < cnt) {                          // tail lanes issue no loads
                int2 v = escr[wid][j];
                float a = __int_as_float(v.y);
                uint4 hv = *(const uint4*)&h0b[(size_t)v.x * 64 + cg * 8];
                float c0 = __uint_as_float(hv.x << 16);
                float c1 = __uint_as_float(hv.x & 0xFFFF0000u);
                float c2 = __uint_as_float(hv.y << 16);
                float c3 = __uint_as_float(hv.y & 0xFFFF0000u);
                float c4 = __uint_as_float(hv.z << 16);
                float c5 = __uint_as_float(hv.z & 0xFFFF0000u);
                float c6 = __uint_as_float(hv.w << 16);
                float c7 = __uint_as_float(hv.w & 0xFFFF0000u);
                accA.x = fmaf(a, c0, accA.x);
                accA.y = fmaf(a, c1, accA.y);
                accA.z = fmaf(a, c2, accA.z);
                accA.w = fmaf(a, c3, accA.w);
                accB.x = fmaf(a, c4, accB.x);
                accB.y = fmaf(a, c5, accB.y);
                accB.z = fmaf(a, c6, accB.z);
                accB.w = fmaf(a, c7, accB.w);
            }
        }
    }
#pragma unroll
    for (int off = 32; off > 0; off >>= 1) esum += __shfl_xor(esum, off, 64);
    const float inv = 1.0f / esum;
#pragma unroll
    for (int off = 8; off < 64; off <<= 1) {        // reduce over 8 edge slots
        accA.x += __shfl_xor(accA.x, off, 64);
        accA.y += __shfl_xor(accA.y, off, 64);
        accA.z += __shfl_xor(accA.z, off, 64);
        accA.w += __shfl_xor(accA.w, off, 64);
        accB.x += __shfl_xor(accB.x, off, 64);
        accB.y += __shfl_xor(accB.y, off, 64);
        accB.z += __shfl_xor(accB.z, off, 64);
        accB.w += __shfl_xor(accB.w, off, 64);
    }
    // normalize + relu, park row in LDS
    if (sg == 0) {
        float4 rA, rB;
        rA.x = fmaxf(accA.x * inv, 0.0f);
        rA.y = fmaxf(accA.y * inv, 0.0f);
        rA.z = fmaxf(accA.z * inv, 0.0f);
        rA.w = fmaxf(accA.w * inv, 0.0f);
        rB.x = fmaxf(accB.x * inv, 0.0f);
        rB.y = fmaxf(accB.y * inv, 0.0f);
        rB.z = fmaxf(accB.z * inv, 0.0f);
        rB.w = fmaxf(accB.w * inv, 0.0f);
        *(float4*)&rowbuf[wid][cg * 8]     = rA;
        *(float4*)&rowbuf[wid][cg * 8 + 4] = rB;
    }

    // ---- fused gemm1: h1[n,oc] = sum_k row[k] * W1[oc,k] ----
    const int oc = lane;                 // lanes 40..63 hit zero-padded W1 rows
    float hacc = 0.0f;
#pragma unroll
    for (int k4 = 0; k4 < 16; ++k4) {
        float4 rv = *(const float4*)&rowbuf[wid][k4 * 4];       // broadcast
        float4 wv = *(const float4*)&W1L[oc * 68 + k4 * 4];
        hacc = fmaf(rv.x, wv.x, hacc);
        hacc = fmaf(rv.y, wv.y, hacc);
        hacc = fmaf(rv.z, wv.z, hacc);
        hacc = fmaf(rv.w, wv.w, hacc);
    }

    const bool ocOK = (oc < 40);
    if (ocOK) h1b[(size_t)n * 40 + oc] = f2bf(hacc);
    float pai = ocOK ? hacc * att1[oc]      : 0.0f;
    float paj = ocOK ? hacc * att1[40 + oc] : 0.0f;
#pragma unroll
    for (int off = 1; off < 64; off <<= 1) {
        pai += __shfl_xor(pai, off, 64);
        paj += __shfl_xor(paj, off, 64);
    }
    if (lane == 0) { ai1[n] = pai; aj1[n] = paj; }
}

// ===========================================================================
// Layer-1 aggregation (bf16 h1, 40 ch) + log_softmax.
// 8 edges/trip x 5 active lanes/edge (uint4 = 8ch), guarded tail.
// ===========================================================================
__global__ __launch_bounds__(256) void agg_lsm(
        const int* __restrict__ rowstart, const int* __restrict__ csr_src,
        const float* __restrict__ aj,
        const float* __restrict__ ai, const unsigned short* __restrict__ h1b,
        float* __restrict__ out) {
    __shared__ int2 escr[4][64];

    const int lane = threadIdx.x & 63;
    const int wid  = threadIdx.x >> 6;
    const int n = blockIdx.x * 4 + wid;
    if (n >= NNODES) return;

    const int start = rowstart[n];
    const int end   = rowstart[n + 1];
    const float ain = ai[n];

    const int  cg   = lane & 7;
    const int  sg   = lane >> 3;
    const bool chOK = (cg < 5);         // 40 channels = 5 uint4 chunks
    float4 accA = make_float4(0.f, 0.f, 0.f, 0.f);
    float4 accB = make_float4(0.f, 0.f, 0.f, 0.f);
    float  esum = 0.0f;

    for (int c = start; c < end; c += 64) {
        int rem = end - c;
        int cnt = (rem < 64) ? rem : 64;
        int s = 0; float e = 0.0f;
        if (lane < cnt) {
            s = csr_src[c + lane];
            float t = ain + aj[s];
            t = (t > 0.0f) ? t : 0.2f * t;
            e = __expf(t);
        }
        escr[wid][lane] = make_int2(s, __float_as_int(e));
        esum += e;
        for (int j0 = 0; j0 < cnt; j0 += 8) {
            int j = j0 + sg;
            if (chOK && j < cnt) {
                int2 v = escr[wid][j];
                float a = __int_as_float(v.y);
                uint4 hv = *(const uint4*)&h1b[(size_t)v.x * 40 + cg * 8];
                float c0 = __uint_as_float(hv.x << 16);
                float c1 = __uint_as_float(hv.x & 0xFFFF0000u);
                float c2 = __uint_as_float(hv.y << 16);
                float c3 = __uint_as_float(hv.y & 0xFFFF0000u);
                float c4 = __uint_as_float(hv.z << 16);
                float c5 = __uint_as_float(hv.z & 0xFFFF0000u);
                float c6 = __uint_as_float(hv.w << 16);
                float c7 = __uint_as_float(hv.w & 0xFFFF0000u);
                accA.x = fmaf(a, c0, accA.x);
                accA.y = fmaf(a, c1, accA.y);
                accA.z = fmaf(a, c2, accA.z);
                accA.w = fmaf(a, c3, accA.w);
                accB.x = fmaf(a, c4, accB.x);
                accB.y = fmaf(a, c5, accB.y);
                accB.z = fmaf(a, c6, accB.z);
                accB.w = fmaf(a, c7, accB.w);
            }
        }
    }
#pragma unroll
    for (int off = 32; off > 0; off >>= 1) esum += __shfl_xor(esum, off, 64);
    const float inv = 1.0f / esum;
#pragma unroll
    for (int off = 8; off < 64; off <<= 1) {
        accA.x += __shfl_xor(accA.x, off, 64);
        accA.y += __shfl_xor(accA.y, off, 64);
        accA.z += __shfl_xor(accA.z, off, 64);
        accA.w += __shfl_xor(accA.w, off, 64);
        accB.x += __shfl_xor(accB.x, off, 64);
        accB.y += __shfl_xor(accB.y, off, 64);
        accB.z += __shfl_xor(accB.z, off, 64);
        accB.w += __shfl_xor(accB.w, off, 64);
    }
    accA.x *= inv; accA.y *= inv; accA.z *= inv; accA.w *= inv;
    accB.x *= inv; accB.y *= inv; accB.z *= inv; accB.w *= inv;

    // log_softmax over 40 values (5 uint4 chunks in lanes cg<5; values
    // replicated across all 8 sg groups after the xor-reduce)
    float mx = -INFINITY;
    if (chOK) {
        mx = fmaxf(fmaxf(fmaxf(accA.x, accA.y), fmaxf(accA.z, accA.w)),
                   fmaxf(fmaxf(accB.x, accB.y), fmaxf(accB.z, accB.w)));
    }
#pragma unroll
    for (int off = 1; off < 8; off <<= 1) mx = fmaxf(mx, __shfl_xor(mx, off, 64));
    float sm = 0.0f;
    if (chOK) {
        sm = __expf(accA.x - mx) + __expf(accA.y - mx) +
             __expf(accA.z - mx) + __expf(accA.w - mx) +
             __expf(accB.x - mx) + __expf(accB.y - mx) +
             __expf(accB.z - mx) + __expf(accB.w - mx);
    }
#pragma unroll
    for (int off = 1; off < 8; off <<= 1) sm += __shfl_xor(sm, off, 64);
    float ls = mx + logf(sm);
    if (sg == 0 && chOK) {
        float4 oA = make_float4(accA.x - ls, accA.y - ls, accA.z - ls, accA.w - ls);
        float4 oB = make_float4(accB.x - ls, accB.y - ls, accB.z - ls, accB.w - ls);
        *(float4*)&out[(size_t)n * 40 + cg * 8]     = oA;
        *(float4*)&out[(size_t)n * 40 + cg * 8 + 4] = oB;
    }
}

// ===========================================================================
extern "C" void kernel_launch(void* const* d_in, const int* in_sizes, int n_in,
                              void* d_out, int out_size, void* d_ws, size_t ws_size,
                              hipStream_t stream) {
    const float* x    = (const float*)d_in[0];
    const int*   ei   = (const int*)  d_in[1];
    const float* W0   = (const float*)d_in[2];
    const float* att0 = (const float*)d_in[3];
    const float* W1   = (const float*)d_in[4];
    const float* att1 = (const float*)d_in[5];
    float* out = (float*)d_out;

    // workspace layout (16B-aligned segments)
    int* wi = (int*)d_ws;
    int*  cnt      = wi;                        // 100352
    int*  bstart   = cnt + 100352;              // 1024
    int*  rowstart = bstart + 1024;             // 100352
    unsigned int* stage = (unsigned int*)(rowstart + 100352);     // KBUCK*NSUB*CAPS
    int*  csr_src  = (int*)(stage + (size_t)KBUCK * NSUB * CAPS); // 1,700,096
    unsigned short* h0b = (unsigned short*)(csr_src + 1700096);   // N*64 bf16 (12.8MB)
    unsigned short* h1b = h0b + (size_t)NNODES * 64;              // N*40 bf16 (8MB)
    float* fbase = (float*)(h1b + (size_t)NNODES * 40);           // 20.8MB total -> 16B aligned
    float* ai0 = fbase;
    float* aj0 = ai0 + 100352;
    float* ai1 = aj0 + 100352;
    float* aj1 = ai1 + 100352;

    const int B = 256;
    const int aggGrid = (NNODES + 3) / 4;

    // ---- CSR build + layer-0 GEMM (now separate kernels for attribution) ----
    zero_cnt<<<(KBUCK * NSUB * CPAD + B - 1) / B, B, 0, stream>>>(cnt);
    bucket_build<<<BUCKB, B, 0, stream>>>(ei, cnt, stage);
    gemm0_k<<<GEMMB, B, 0, stream>>>(x, W0, att0, h0b, ai0, aj0);
    bucket_scan<<<1, 1024, 0, stream>>>(cnt, bstart);
    bucket_scatter<<<KBUCK, B, 0, stream>>>(cnt, bstart, stage, rowstart, csr_src);

    // ---- layer-0 aggregation + fused gemm1 + layer-1 attention scalars ----
    agg_gemm1<<<aggGrid, B, 0, stream>>>(rowstart, csr_src, aj0, ai0, h0b,
                                         W1, att1, h1b, ai1, aj1);

    // ---- layer-1 aggregation + log_softmax ----
    agg_lsm<<<aggGrid, B, 0, stream>>>(rowstart, csr_src, aj1, ai1, h1b, out);
}

// Round 5
// 378.530 us; speedup vs baseline: 1.0676x; 1.0676x over previous
//
#include <hip/hip_runtime.h>
#include <math.h>

#define NNODES 100000
#define NEDGES 1600000
#define ETOT   (NEDGES + NNODES)   // self-loops appended

// bucket-major CSR build
#define BSZ   128                         // dst nodes per bucket (dst >> 7)
#define KBUCK ((NNODES + BSZ - 1) / BSZ)  // 782 buckets
#define CAP   2816                        // max TOTAL entries per bucket
#define NSUB  8                           // per-XCD sub-buckets
#define CAPS  768                         // per sub-bucket (survives XCD skew; R6 lesson)
#define CPAD  16                          // counter padding (one per 64B line)

#define GEMMB 1563                        // gemm0 blocks (64 nodes each)
#define EPT   4                           // edges per thread in bucket half
#define BUCKB ((ETOT + 1024 - 1) / 1024)  // 1661 bucket blocks
#define GGRP  ((GEMMB + 7) / 8)           // 196 gemm groups-of-8
#define BGRP  ((BUCKB + 7) / 8)           // 208 bucket groups-of-8

__device__ __forceinline__ int xcc_id() {
    int x;
    asm volatile("s_getreg_b32 %0, hwreg(HW_REG_XCC_ID)" : "=s"(x));
    return x & (NSUB - 1);
}

// fp32 -> bf16 with round-to-nearest-even (bit-level, no NaN inputs here)
__device__ __forceinline__ unsigned short f2bf(float f) {
    unsigned u = __float_as_uint(f);
    return (unsigned short)((u + 0x7FFFu + ((u >> 16) & 1u)) >> 16);
}

// ===========================================================================
__global__ void zero_cnt(int* __restrict__ cnt) {
    int i = blockIdx.x * blockDim.x + threadIdx.x;
    if (i < KBUCK * NSUB * CPAD) cnt[i] = 0;
}

// ---------------------------------------------------------------------------
// bucket half: append (dst-low, src) to XCD-local sub-bucket. 4-edge ILP.
__device__ __forceinline__ void bucket_body(int bb, const int* __restrict__ ei,
                                            int* __restrict__ cnt,
                                            unsigned int* __restrict__ stage) {
    const int t = threadIdx.x;
    const int xg = xcc_id();
#pragma unroll
    for (int r = 0; r < EPT; ++r) {
        int e = bb * 1024 + r * 256 + t;
        if (e < ETOT) {
            int src, dst;
            if (e < NEDGES) { src = ei[e]; dst = ei[NEDGES + e]; }
            else            { src = dst = e - NEDGES; }
            int sb = (dst >> 7) * NSUB + xg;
            int pos = atomicAdd(&cnt[sb * CPAD], 1);
            if (pos < CAPS)
                stage[(size_t)sb * CAPS + pos] =
                    ((unsigned)(dst & 127) << 24) | (unsigned)src;
        }
    }
}

// ---------------------------------------------------------------------------
// gemm half: h0 = x @ W0.T (64 out-ch, stored bf16) + attention scalars.
// R4 body: full-K LDS staging + 3-deep x register prefetch pipeline.
__device__ __forceinline__ void gemm0_body(int gb, const float* __restrict__ x,
                                           const float* __restrict__ W,
                                           const float* __restrict__ att,
                                           unsigned short* __restrict__ h0b,
                                           float* __restrict__ ai,
                                           float* __restrict__ aj) {
    __shared__ float Wt[128 * 68];
    const int tid = threadIdx.x;
    const int nb = gb * 64;

    const int lane = tid & 63;
    const int w    = tid >> 6;
    const int ocg  = lane & 15;          // owns out-ch ocg*4 .. ocg*4+3
    const int ng   = lane >> 4;
    const int nodeLocal = w * 16 + ng * 4;

    const float* xp[4];
#pragma unroll
    for (int j = 0; j < 4; ++j) {
        int node = nb + nodeLocal + j;
        xp[j] = x + (size_t)(node < NNODES ? node : NNODES - 1) * 128;
    }

    // x pipeline issued BEFORE W staging (overlaps stage + barrier)
    float4 xa[4], xb[4], xc[4];
#pragma unroll
    for (int j = 0; j < 4; ++j) {
        xa[j] = *(const float4*)(xp[j] + 0);
        xb[j] = *(const float4*)(xp[j] + 4);
        xc[j] = *(const float4*)(xp[j] + 8);
    }

    for (int i = tid; i < 128 * 64; i += 256) {
        int oc = i >> 7, k = i & 127;
        Wt[k * 68 + oc] = W[i];
    }
    __syncthreads();

    float4 acc[4];
#pragma unroll
    for (int j = 0; j < 4; ++j) acc[j] = make_float4(0.f, 0.f, 0.f, 0.f);

#pragma unroll 4
    for (int k4 = 0; k4 < 32; ++k4) {
        const int kb = k4 * 4;
        int kpf = kb + 12; if (kpf > 124) kpf = 124;
        float4 xn0 = *(const float4*)(xp[0] + kpf);
        float4 xn1 = *(const float4*)(xp[1] + kpf);
        float4 xn2 = *(const float4*)(xp[2] + kpf);
        float4 xn3 = *(const float4*)(xp[3] + kpf);
        float4 wv0 = *(const float4*)&Wt[(kb + 0) * 68 + ocg * 4];
        float4 wv1 = *(const float4*)&Wt[(kb + 1) * 68 + ocg * 4];
        float4 wv2 = *(const float4*)&Wt[(kb + 2) * 68 + ocg * 4];
        float4 wv3 = *(const float4*)&Wt[(kb + 3) * 68 + ocg * 4];
#pragma unroll
        for (int j = 0; j < 4; ++j) {
            float4 xv = xa[j];
            acc[j].x += xv.x * wv0.x + xv.y * wv1.x + xv.z * wv2.x + xv.w * wv3.x;
            acc[j].y += xv.x * wv0.y + xv.y * wv1.y + xv.z * wv2.y + xv.w * wv3.y;
            acc[j].z += xv.x * wv0.z + xv.y * wv1.z + xv.z * wv2.z + xv.w * wv3.z;
            acc[j].w += xv.x * wv0.w + xv.y * wv1.w + xv.z * wv2.w + xv.w * wv3.w;
        }
        xa[0] = xb[0]; xa[1] = xb[1]; xa[2] = xb[2]; xa[3] = xb[3];
        xb[0] = xc[0]; xb[1] = xc[1]; xb[2] = xc[2]; xb[3] = xc[3];
        xc[0] = xn0;   xc[1] = xn1;   xc[2] = xn2;   xc[3] = xn3;
    }

    const int ocb = ocg * 4;
    float ati[4], atj[4];
#pragma unroll
    for (int i = 0; i < 4; ++i) {
        ati[i] = att[ocb + i];
        atj[i] = att[64 + ocb + i];
    }

#pragma unroll
    for (int j = 0; j < 4; ++j) {
        int nodeG = nb + nodeLocal + j;
        float pai = acc[j].x * ati[0] + acc[j].y * ati[1] + acc[j].z * ati[2] + acc[j].w * ati[3];
        float paj = acc[j].x * atj[0] + acc[j].y * atj[1] + acc[j].z * atj[2] + acc[j].w * atj[3];
#pragma unroll
        for (int off = 1; off < 16; off <<= 1) {
            pai += __shfl_xor(pai, off, 64);
            paj += __shfl_xor(paj, off, 64);
        }
        if (nodeG < NNODES) {
            unsigned p0 = ((unsigned)f2bf(acc[j].y) << 16) | f2bf(acc[j].x);
            unsigned p1 = ((unsigned)f2bf(acc[j].w) << 16) | f2bf(acc[j].z);
            *(uint2*)&h0b[(size_t)nodeG * 64 + ocb] = make_uint2(p0, p1);
            if (ocg == 0) { ai[nodeG] = pai; aj[nodeG] = paj; }
        }
    }
}

// ---------------------------------------------------------------------------
// Fused heterogeneous kernel (R4: re-fused — split cost ~18us; overlap is real)
__global__ __launch_bounds__(256) void fusedA(
        const int* __restrict__ ei, int* __restrict__ cnt,
        unsigned int* __restrict__ stage,
        const float* __restrict__ x, const float* __restrict__ W0,
        const float* __restrict__ att0,
        unsigned short* __restrict__ h0b, float* __restrict__ ai0,
        float* __restrict__ aj0) {
    const int bid = blockIdx.x;
    const int grp = bid >> 3, sub = bid & 7;
    if ((grp & 1) && (grp >> 1) < GGRP) {
        int g = (grp >> 1) * 8 + sub;
        if (g < GEMMB) gemm0_body(g, x, W0, att0, h0b, ai0, aj0);
    } else {
        int bg = grp - min(GGRP, (grp + 1) >> 1);
        int bb = bg * 8 + sub;
        if (bb < BUCKB) bucket_body(bb, ei, cnt, stage);
    }
}

// ===========================================================================
__global__ void bucket_scan(const int* __restrict__ cnt, int* __restrict__ bstart) {
    __shared__ int wsum[16];
    const int t = threadIdx.x;                      // 1024 threads
    int x = 0;
    if (t < KBUCK) {
#pragma unroll
        for (int s = 0; s < NSUB; ++s) x += min(cnt[(t * NSUB + s) * CPAD], CAPS);
    }
    int lane = t & 63, w = t >> 6;
    int inc = x;
#pragma unroll
    for (int off = 1; off < 64; off <<= 1) {
        int u = __shfl_up(inc, off, 64);
        if (lane >= off) inc += u;
    }
    if (lane == 63) wsum[w] = inc;
    __syncthreads();
    if (t == 0) {
        int s = 0;
#pragma unroll
        for (int j = 0; j < 16; ++j) { int y = wsum[j]; wsum[j] = s; s += y; }
    }
    __syncthreads();
    int excl = inc - x + wsum[w];
    if (t < KBUCK) bstart[t] = excl;
    if (t == KBUCK) bstart[KBUCK] = excl;
}

__global__ __launch_bounds__(256) void bucket_scatter(
        const int* __restrict__ cnt, const int* __restrict__ bstart,
        const unsigned int* __restrict__ stage, int* __restrict__ rowstart,
        int* __restrict__ csr_src) {
    __shared__ unsigned int ent[CAP];
    __shared__ int hist[BSZ];
    __shared__ int scnt[NSUB];
    __shared__ int soff[NSUB + 1];
    __shared__ int wtot;
    const int b = blockIdx.x, t = threadIdx.x;
    const int n0 = b * BSZ;
    const int base = bstart[b];

    if (t < BSZ) hist[t] = 0;
    if (t < NSUB) scnt[t] = min(cnt[(b * NSUB + t) * CPAD], CAPS);
    __syncthreads();
    if (t == 0) {
        int s = 0;
#pragma unroll
        for (int x = 0; x < NSUB; ++x) { soff[x] = s; s += scnt[x]; }
        soff[NSUB] = s;
    }
    __syncthreads();

#pragma unroll
    for (int x = 0; x < NSUB; ++x) {
        const int cx = scnt[x];
        const int ox = soff[x];
        const unsigned int* sp = stage + (size_t)(b * NSUB + x) * CAPS;
        for (int i = t; i < cx; i += 256) {
            unsigned int v = sp[i];
            ent[ox + i] = v;
            atomicAdd(&hist[v >> 24], 1);
        }
    }
    __syncthreads();
    const int c = soff[NSUB];

    int lane = t & 63, w = t >> 6;
    int v = (t < BSZ) ? hist[t] : 0;
    int inc = v;
#pragma unroll
    for (int off = 1; off < 64; off <<= 1) {
        int u = __shfl_up(inc, off, 64);
        if (lane >= off) inc += u;
    }
    if (t == 63) wtot = inc;
    __syncthreads();
    int excl = inc - v + ((w == 1) ? wtot : 0);
    if (t < BSZ) {
        int node = n0 + t;
        if (node <= NNODES) rowstart[node] = base + excl;
    }
    __syncthreads();
    if (t < BSZ) hist[t] = excl;
    __syncthreads();
    for (int i = t; i < c; i += 256) {
        unsigned int e = ent[i];
        int pos = atomicAdd(&hist[e >> 24], 1);
        csr_src[base + pos] = (int)(e & 0xFFFFFFu);
    }
}

// ===========================================================================
// Layer-0 aggregation + fused gemm1 -> bf16 h1 + layer-1 attention scalars.
// R4 restructure: NO escr LDS round-trip. Per 8-edge trip, each lane gets its
// edge via __shfl (ds_bpermute) and computes alpha redundantly (8 lanes/edge)
// so the aj gather and h0b gather issue IN PARALLEL (one serial latency link
// removed). esum counted 8x per edge -> inv = 8/sum.
// ===========================================================================
__global__ __launch_bounds__(256) void agg_gemm1(
        const int* __restrict__ rowstart, const int* __restrict__ csr_src,
        const float* __restrict__ aj,
        const float* __restrict__ ai, const unsigned short* __restrict__ h0b,
        const float* __restrict__ W1, const float* __restrict__ att1,
        unsigned short* __restrict__ h1b, float* __restrict__ ai1,
        float* __restrict__ aj1) {
    __shared__ float  W1L[64 * 68];     // oc-major, stride 68 (2-way banks: free)
    __shared__ float  rowbuf[4][64];    // per-wave combined row

    const int tid = threadIdx.x;
    for (int i = tid; i < 64 * 64; i += 256) {
        int oc = i >> 6, k = i & 63;
        W1L[oc * 68 + k] = (oc < 40) ? W1[oc * 64 + k] : 0.0f;
    }
    __syncthreads();

    const int lane = tid & 63;
    const int wid  = tid >> 6;
    const int n = blockIdx.x * 4 + wid;
    if (n >= NNODES) return;

    const int start = rowstart[n];
    const int end   = rowstart[n + 1];
    const float ain = ai[n];

    const int cg = lane & 7;            // 8 channel-groups of 8 ch
    const int sg = lane >> 3;           // 8 edge slots
    const int cgo = cg << 3;            // channel offset
    float4 accA = make_float4(0.f, 0.f, 0.f, 0.f);
    float4 accB = make_float4(0.f, 0.f, 0.f, 0.f);
    float  esum = 0.0f;

    for (int c = start; c < end; c += 64) {
        int rem = end - c;
        int cnt = (rem < 64) ? rem : 64;            // wave-uniform
        int s = (lane < cnt) ? csr_src[c + lane] : 0;
        for (int j0 = 0; j0 < cnt; j0 += 8) {
            int j  = j0 + sg;
            int sj = __shfl(s, j, 64);              // bpermute, no LDS alloc
            if (j < cnt) {
                float ajv = aj[sj];                 // 8 lanes same addr
                uint4 hv = *(const uint4*)&h0b[(unsigned)(sj << 6) + cgo];
                float t = ain + ajv;
                t = (t > 0.0f) ? t : 0.2f * t;
                float a = __expf(t);                // overlaps hv latency
                esum += a;
                float c0 = __uint_as_float(hv.x << 16);
                float c1 = __uint_as_float(hv.x & 0xFFFF0000u);
                float c2 = __uint_as_float(hv.y << 16);
                float c3 = __uint_as_float(hv.y & 0xFFFF0000u);
                float c4 = __uint_as_float(hv.z << 16);
                float c5 = __uint_as_float(hv.z & 0xFFFF0000u);
                float c6 = __uint_as_float(hv.w << 16);
                float c7 = __uint_as_float(hv.w & 0xFFFF0000u);
                accA.x = fmaf(a, c0, accA.x);
                accA.y = fmaf(a, c1, accA.y);
                accA.z = fmaf(a, c2, accA.z);
                accA.w = fmaf(a, c3, accA.w);
                accB.x = fmaf(a, c4, accB.x);
                accB.y = fmaf(a, c5, accB.y);
                accB.z = fmaf(a, c6, accB.z);
                accB.w = fmaf(a, c7, accB.w);
            }
        }
    }
#pragma unroll
    for (int off = 32; off > 0; off >>= 1) esum += __shfl_xor(esum, off, 64);
    const float inv = 8.0f / esum;                  // each edge counted 8x
#pragma unroll
    for (int off = 8; off < 64; off <<= 1) {        // reduce over 8 edge slots
        accA.x += __shfl_xor(accA.x, off, 64);
        accA.y += __shfl_xor(accA.y, off, 64);
        accA.z += __shfl_xor(accA.z, off, 64);
        accA.w += __shfl_xor(accA.w, off, 64);
        accB.x += __shfl_xor(accB.x, off, 64);
        accB.y += __shfl_xor(accB.y, off, 64);
        accB.z += __shfl_xor(accB.z, off, 64);
        accB.w += __shfl_xor(accB.w, off, 64);
    }
    // normalize + relu, park row in LDS
    if (sg == 0) {
        float4 rA, rB;
        rA.x = fmaxf(accA.x * inv, 0.0f);
        rA.y = fmaxf(accA.y * inv, 0.0f);
        rA.z = fmaxf(accA.z * inv, 0.0f);
        rA.w = fmaxf(accA.w * inv, 0.0f);
        rB.x = fmaxf(accB.x * inv, 0.0f);
        rB.y = fmaxf(accB.y * inv, 0.0f);
        rB.z = fmaxf(accB.z * inv, 0.0f);
        rB.w = fmaxf(accB.w * inv, 0.0f);
        *(float4*)&rowbuf[wid][cgo]     = rA;
        *(float4*)&rowbuf[wid][cgo + 4] = rB;
    }

    // ---- fused gemm1: h1[n,oc] = sum_k row[k] * W1[oc,k] ----
    const int oc = lane;                 // lanes 40..63 hit zero-padded W1 rows
    float hacc = 0.0f;
#pragma unroll
    for (int k4 = 0; k4 < 16; ++k4) {
        float4 rv = *(const float4*)&rowbuf[wid][k4 * 4];       // broadcast
        float4 wv = *(const float4*)&W1L[oc * 68 + k4 * 4];
        hacc = fmaf(rv.x, wv.x, hacc);
        hacc = fmaf(rv.y, wv.y, hacc);
        hacc = fmaf(rv.z, wv.z, hacc);
        hacc = fmaf(rv.w, wv.w, hacc);
    }

    const bool ocOK = (oc < 40);
    if (ocOK) h1b[(size_t)n * 40 + oc] = f2bf(hacc);
    float pai = ocOK ? hacc * att1[oc]      : 0.0f;
    float paj = ocOK ? hacc * att1[40 + oc] : 0.0f;
#pragma unroll
    for (int off = 1; off < 64; off <<= 1) {
        pai += __shfl_xor(pai, off, 64);
        paj += __shfl_xor(paj, off, 64);
    }
    if (lane == 0) { ai1[n] = pai; aj1[n] = paj; }
}

// ===========================================================================
// Layer-1 aggregation (bf16 h1, 40 ch) + log_softmax. Same R4 restructure:
// no LDS, shfl edge broadcast, parallel aj/h1b gathers, 8x-counted esum.
// ===========================================================================
__global__ __launch_bounds__(256) void agg_lsm(
        const int* __restrict__ rowstart, const int* __restrict__ csr_src,
        const float* __restrict__ aj,
        const float* __restrict__ ai, const unsigned short* __restrict__ h1b,
        float* __restrict__ out) {
    const int lane = threadIdx.x & 63;
    const int wid  = threadIdx.x >> 6;
    const int n = blockIdx.x * 4 + wid;
    if (n >= NNODES) return;

    const int start = rowstart[n];
    const int end   = rowstart[n + 1];
    const float ain = ai[n];

    const int  cg   = lane & 7;
    const int  sg   = lane >> 3;
    const bool chOK = (cg < 5);         // 40 channels = 5 uint4 chunks
    float4 accA = make_float4(0.f, 0.f, 0.f, 0.f);
    float4 accB = make_float4(0.f, 0.f, 0.f, 0.f);
    float  esum = 0.0f;

    for (int c = start; c < end; c += 64) {
        int rem = end - c;
        int cnt = (rem < 64) ? rem : 64;
        int s = (lane < cnt) ? csr_src[c + lane] : 0;
        for (int j0 = 0; j0 < cnt; j0 += 8) {
            int j  = j0 + sg;
            int sj = __shfl(s, j, 64);
            if (j < cnt) {
                float ajv = aj[sj];
                float t = ain + ajv;
                t = (t > 0.0f) ? t : 0.2f * t;
                float a = __expf(t);
                esum += a;                          // 8x per edge (all cg lanes)
                if (chOK) {
                    uint4 hv = *(const uint4*)&h1b[(unsigned)(sj * 40) + (cg << 3)];
                    float c0 = __uint_as_float(hv.x << 16);
                    float c1 = __uint_as_float(hv.x & 0xFFFF0000u);
                    float c2 = __uint_as_float(hv.y << 16);
                    float c3 = __uint_as_float(hv.y & 0xFFFF0000u);
                    float c4 = __uint_as_float(hv.z << 16);
                    float c5 = __uint_as_float(hv.z & 0xFFFF0000u);
                    float c6 = __uint_as_float(hv.w << 16);
                    float c7 = __uint_as_float(hv.w & 0xFFFF0000u);
                    accA.x = fmaf(a, c0, accA.x);
                    accA.y = fmaf(a, c1, accA.y);
                    accA.z = fmaf(a, c2, accA.z);
                    accA.w = fmaf(a, c3, accA.w);
                    accB.x = fmaf(a, c4, accB.x);
                    accB.y = fmaf(a, c5, accB.y);
                    accB.z = fmaf(a, c6, accB.z);
                    accB.w = fmaf(a, c7, accB.w);
                }
            }
        }
    }
#pragma unroll
    for (int off = 32; off > 0; off >>= 1) esum += __shfl_xor(esum, off, 64);
    const float inv = 8.0f / esum;                  // each edge counted 8x
#pragma unroll
    for (int off = 8; off < 64; off <<= 1) {
        accA.x += __shfl_xor(accA.x, off, 64);
        accA.y += __shfl_xor(accA.y, off, 64);
        accA.z += __shfl_xor(accA.z, off, 64);
        accA.w += __shfl_xor(accA.w, off, 64);
        accB.x += __shfl_xor(accB.x, off, 64);
        accB.y += __shfl_xor(accB.y, off, 64);
        accB.z += __shfl_xor(accB.z, off, 64);
        accB.w += __shfl_xor(accB.w, off, 64);
    }
    accA.x *= inv; accA.y *= inv; accA.z *= inv; accA.w *= inv;
    accB.x *= inv; accB.y *= inv; accB.z *= inv; accB.w *= inv;

    // log_softmax over 40 values (5 uint4 chunks in lanes cg<5; values
    // replicated across all 8 sg groups after the xor-reduce)
    float mx = -INFINITY;
    if (chOK) {
        mx = fmaxf(fmaxf(fmaxf(accA.x, accA.y), fmaxf(accA.z, accA.w)),
                   fmaxf(fmaxf(accB.x, accB.y), fmaxf(accB.z, accB.w)));
    }
#pragma unroll
    for (int off = 1; off < 8; off <<= 1) mx = fmaxf(mx, __shfl_xor(mx, off, 64));
    float sm = 0.0f;
    if (chOK) {
        sm = __expf(accA.x - mx) + __expf(accA.y - mx) +
             __expf(accA.z - mx) + __expf(accA.w - mx) +
             __expf(accB.x - mx) + __expf(accB.y - mx) +
             __expf(accB.z - mx) + __expf(accB.w - mx);
    }
#pragma unroll
    for (int off = 1; off < 8; off <<= 1) sm += __shfl_xor(sm, off, 64);
    float ls = mx + logf(sm);
    if (sg == 0 && chOK) {
        float4 oA = make_float4(accA.x - ls, accA.y - ls, accA.z - ls, accA.w - ls);
        float4 oB = make_float4(accB.x - ls, accB.y - ls, accB.z - ls, accB.w - ls);
        *(float4*)&out[(size_t)n * 40 + (cg << 3)]     = oA;
        *(float4*)&out[(size_t)n * 40 + (cg << 3) + 4] = oB;
    }
}

// ===========================================================================
extern "C" void kernel_launch(void* const* d_in, const int* in_sizes, int n_in,
                              void* d_out, int out_size, void* d_ws, size_t ws_size,
                              hipStream_t stream) {
    const float* x    = (const float*)d_in[0];
    const int*   ei   = (const int*)  d_in[1];
    const float* W0   = (const float*)d_in[2];
    const float* att0 = (const float*)d_in[3];
    const float* W1   = (const float*)d_in[4];
    const float* att1 = (const float*)d_in[5];
    float* out = (float*)d_out;

    // workspace layout (16B-aligned segments)
    int* wi = (int*)d_ws;
    int*  cnt      = wi;                        // 100352
    int*  bstart   = cnt + 100352;              // 1024
    int*  rowstart = bstart + 1024;             // 100352
    unsigned int* stage = (unsigned int*)(rowstart + 100352);     // KBUCK*NSUB*CAPS
    int*  csr_src  = (int*)(stage + (size_t)KBUCK * NSUB * CAPS); // 1,700,096
    unsigned short* h0b = (unsigned short*)(csr_src + 1700096);   // N*64 bf16 (12.8MB)
    unsigned short* h1b = h0b + (size_t)NNODES * 64;              // N*40 bf16 (8MB)
    float* fbase = (float*)(h1b + (size_t)NNODES * 40);           // 20.8MB total -> 16B aligned
    float* ai0 = fbase;
    float* aj0 = ai0 + 100352;
    float* ai1 = aj0 + 100352;
    float* aj1 = ai1 + 100352;

    const int B = 256;
    const int aggGrid = (NNODES + 3) / 4;
    const int fusedGrid = (GGRP + BGRP) * 8;

    // ---- CSR build (bucket half) fused with layer-0 GEMM (independent) ----
    zero_cnt<<<(KBUCK * NSUB * CPAD + B - 1) / B, B, 0, stream>>>(cnt);
    fusedA<<<fusedGrid, B, 0, stream>>>(ei, cnt, stage, x, W0, att0, h0b, ai0, aj0);
    bucket_scan<<<1, 1024, 0, stream>>>(cnt, bstart);
    bucket_scatter<<<KBUCK, B, 0, stream>>>(cnt, bstart, stage, rowstart, csr_src);

    // ---- layer-0 aggregation + fused gemm1 + layer-1 attention scalars ----
    agg_gemm1<<<aggGrid, B, 0, stream>>>(rowstart, csr_src, aj0, ai0, h0b,
                                         W1, att1, h1b, ai1, aj1);

    // ---- layer-1 aggregation + log_softmax ----
    agg_lsm<<<aggGrid, B, 0, stream>>>(rowstart, csr_src, aj1, ai1, h1b, out);
}